// Round 5
// baseline (35252.985 us; speedup 1.0000x reference)
//
#include <hip/hip_runtime.h>
#include <hip/hip_cooperative_groups.h>
#include <cmath>

namespace cg = cooperative_groups;

#define T_STEPS 1024
#define BATCH   128
#define IN_DIM  128
#define HID     256
#define OUT_DIM 128
#define KDEPTH  32
#define KTOT    384

#define NBLK 256
#define NTHR 512

#define SA   388      // act row stride (floats)
#define WST  36       // wtT row stride: [384][36], k-major
#define SOW  260      // wo row stride
#define PSTR 36       // partials col stride
#define GBS  33       // gate buffer row stride

#define OFF_WT   0
#define OFF_WO   (384*WST)                 // 13824
#define OFF_ACT  (OFF_WO + 4*SOW)          // 14864
#define OFF_PART (OFF_ACT + 16*SA)         // 21072
#define OFF_GB   (OFF_PART + 16*16*PSTR)   // 30288
#define OFF_BC   (OFF_GB + 16*GBS)         // 30816
#define SMEM_FLOATS (OFF_BC + 32)
#define SMEM_BYTES  (SMEM_FLOATS*4)        // ~120.5 KB

__device__ __forceinline__ float dot4(float4 a, float4 b, float acc) {
    acc = fmaf(a.x, b.x, acc);
    acc = fmaf(a.y, b.y, acc);
    acc = fmaf(a.z, b.z, acc);
    acc = fmaf(a.w, b.w, acc);
    return acc;
}

__global__ void __launch_bounds__(NTHR, 2)
mlstm_frac_kernel(const float* __restrict__ x,
                  const float* __restrict__ Wx,
                  const float* __restrict__ Wh,
                  const float* __restrict__ bvec,
                  const float* __restrict__ Wdx,
                  const float* __restrict__ Wdh,
                  const float* __restrict__ bd,
                  const float* __restrict__ Wo,
                  const float* __restrict__ bo,
                  float* __restrict__ out)
{
    extern __shared__ float sm[];
    cg::grid_group grid = cg::this_grid();

    const int tid = threadIdx.x;
    const int bt  = blockIdx.x >> 5;   // 0..7  batch tile
    const int cgi = blockIdx.x & 31;   // 0..31 col group
    const int Bb  = bt * 16;
    const int Hb  = cgi * 8;           // 8 h columns
    const int obase = cgi * 4;         // 4 y columns

    // ---- one-time: weights -> LDS ----
    // gates+d, k-major transposed: wtT[k][c], c: 0..7 i, 8..15 o, 16..23 g, 24..31 d
    for (int idx = tid; idx < 384 * 32; idx += NTHR) {
        int k = idx >> 5, c = idx & 31;
        int g = c >> 3, hl = c & 7;
        float v;
        if (g < 3) {
            int gcol = g * HID + Hb + hl;
            v = (k < IN_DIM) ? Wx[k * (3 * HID) + gcol]
                             : Wh[(k - IN_DIM) * (3 * HID) + gcol];
        } else {
            v = (k < IN_DIM) ? Wdx[k * HID + Hb + hl]
                             : Wdh[(k - IN_DIM) * HID + Hb + hl];
        }
        sm[OFF_WT + k * WST + c] = v;
    }
    for (int idx = tid; idx < 4 * 256; idx += NTHR) {
        int oc = idx >> 8, k = idx & 255;
        sm[OFF_WO + oc * SOW + k] = Wo[k * OUT_DIM + obase + oc];
    }
    if (tid < 32) {
        int g = tid >> 3, hl = tid & 7;
        sm[OFF_BC + tid] = (g < 3) ? bvec[g * HID + Hb + hl] : bd[Hb + hl];
    }

    // ---- roles ----
    // main GEMM: 4x4 tile, 16-way k-split
    const int kc = tid >> 5;          // 0..15
    const int pos = tid & 31;
    const int pr = pos >> 3;          // 0..3  batch quad
    const int pc = pos & 7;           // 0..7  col quad
    const int k0 = kc * 24;
    // x prefetch slot: exactly 512 float4s in the 16x128 x-tile, 1/thread
    const int xrow = tid >> 5;        // 0..15
    const int xcol = (tid & 31) * 4;  // 0..124
    // filter (tid<128)
    const int fb = tid >> 3, fh = tid & 7;
    // y (tid>=256): 64 outs x 4-way k-split
    const int jy  = (tid >= 256) ? (tid - 256) : 0;
    const int yout = jy >> 2, ykc = jy & 3;
    const int yb = yout >> 2, yoc = yout & 3;
    const float ybias = bo[obase + yoc];

    float hist[KDEPTH];
#pragma unroll
    for (int j = 0; j < KDEPTH; ++j) hist[j] = 0.0f;

    // d_out layout: y (T*B*O) | h_f (B*H) | hc_f (K*B*H) | d_f (B*H)
    float* ybase = out;
    float* hfin  = out + (size_t)T_STEPS * BATCH * OUT_DIM;
    float* hcf   = hfin + BATCH * HID;
    float* dfin  = hcf + (size_t)KDEPTH * BATCH * HID;
    float* hb0 = hcf;    // borrowed; fully overwritten by hist writes in epilogue
    float* hb1 = hfin;

    float dlast = 0.0f;

    // prefetch x_0 tile slot into registers
    float4 xr = *(const float4*)(x + (size_t)(Bb + xrow) * IN_DIM + xcol);

    for (int t = 0; t < T_STEPS; ++t) {
        const float* hprev = (t & 1) ? hb0 : hb1;

        // ---- stage act[16][384] = x_t || h_{t-1} ----
        // x-part from prefetched register (1 float4/thread)
        *(float4*)(sm + OFF_ACT + xrow * SA + xcol) = xr;
        // h-part (2 float4/thread)
        for (int i = tid; i < 16 * 64; i += NTHR) {
            int row = i >> 6, q = i & 63;
            float4 v;
            if (t > 0)
                v = *(const float4*)(hprev + (size_t)(Bb + row) * HID + q * 4);
            else
                v = make_float4(0.f, 0.f, 0.f, 0.f);
            *(float4*)(sm + OFF_ACT + row * SA + IN_DIM + q * 4) = v;
        }
        // issue prefetch of x_{t+1} (consumed at next iteration's stage;
        // hides HBM latency under GEMM+reduce+filter+grid.sync)
        {
            int tn = (t + 1 < T_STEPS) ? (t + 1) : t;
            xr = *(const float4*)(x + (size_t)tn * BATCH * IN_DIM
                                    + (size_t)(Bb + xrow) * IN_DIM + xcol);
        }
        __syncthreads();

        // ---- main GEMM: 16x32 outputs, 4x4 tile/thread, k in [k0,k0+24) ----
        float acc[4][4];
#pragma unroll
        for (int r = 0; r < 4; ++r)
#pragma unroll
            for (int c = 0; c < 4; ++c) acc[r][c] = 0.f;
        {
            const float* A0 = sm + OFF_ACT + (pr * 4) * SA + k0;
            const float* W0 = sm + OFF_WT + k0 * WST + pc * 4;
#pragma unroll
            for (int q = 0; q < 6; ++q) {
                float4 a0 = *(const float4*)(A0 + 0 * SA + q * 4);
                float4 a1 = *(const float4*)(A0 + 1 * SA + q * 4);
                float4 a2 = *(const float4*)(A0 + 2 * SA + q * 4);
                float4 a3 = *(const float4*)(A0 + 3 * SA + q * 4);
                float4 w0 = *(const float4*)(W0 + (q * 4 + 0) * WST);
                float4 w1 = *(const float4*)(W0 + (q * 4 + 1) * WST);
                float4 w2 = *(const float4*)(W0 + (q * 4 + 2) * WST);
                float4 w3 = *(const float4*)(W0 + (q * 4 + 3) * WST);
#define FMAROW(r, av)                                                      \
                acc[r][0] = fmaf(av.x, w0.x, acc[r][0]);                   \
                acc[r][1] = fmaf(av.x, w0.y, acc[r][1]);                   \
                acc[r][2] = fmaf(av.x, w0.z, acc[r][2]);                   \
                acc[r][3] = fmaf(av.x, w0.w, acc[r][3]);                   \
                acc[r][0] = fmaf(av.y, w1.x, acc[r][0]);                   \
                acc[r][1] = fmaf(av.y, w1.y, acc[r][1]);                   \
                acc[r][2] = fmaf(av.y, w1.z, acc[r][2]);                   \
                acc[r][3] = fmaf(av.y, w1.w, acc[r][3]);                   \
                acc[r][0] = fmaf(av.z, w2.x, acc[r][0]);                   \
                acc[r][1] = fmaf(av.z, w2.y, acc[r][1]);                   \
                acc[r][2] = fmaf(av.z, w2.z, acc[r][2]);                   \
                acc[r][3] = fmaf(av.z, w2.w, acc[r][3]);                   \
                acc[r][0] = fmaf(av.w, w3.x, acc[r][0]);                   \
                acc[r][1] = fmaf(av.w, w3.y, acc[r][1]);                   \
                acc[r][2] = fmaf(av.w, w3.z, acc[r][2]);                   \
                acc[r][3] = fmaf(av.w, w3.w, acc[r][3]);
                FMAROW(0, a0)
                FMAROW(1, a1)
                FMAROW(2, a2)
                FMAROW(3, a3)
#undef FMAROW
            }
        }
        // partials -> LDS
#pragma unroll
        for (int r = 0; r < 4; ++r) {
            *(float4*)(sm + OFF_PART + (kc * 16 + pr * 4 + r) * PSTR + pc * 4) =
                make_float4(acc[r][0], acc[r][1], acc[r][2], acc[r][3]);
        }
        __syncthreads();

        // ---- reduce 16 partials + bias + activation ----
        {
            int row = tid >> 5, c = tid & 31;
            const float* pp = sm + OFF_PART + row * PSTR + c;
            float s0 = 0.f, s1 = 0.f, s2 = 0.f, s3 = 0.f;
#pragma unroll
            for (int k4 = 0; k4 < 16; k4 += 4) {
                s0 += pp[(k4 + 0) * 16 * PSTR];
                s1 += pp[(k4 + 1) * 16 * PSTR];
                s2 += pp[(k4 + 2) * 16 * PSTR];
                s3 += pp[(k4 + 3) * 16 * PSTR];
            }
            float s = (s0 + s1) + (s2 + s3) + sm[OFF_BC + c];
            int g = c >> 3;
            float a;
            if (g == 2) a = tanhf(s);
            else {
                a = 1.0f / (1.0f + expf(-s));
                if (g == 3) a *= 0.5f;
            }
            sm[OFF_GB + row * GBS + c] = a;
        }
        __syncthreads();

        // ---- filter (waves 0-1) ----
        if (tid < 128) {
            const float* gb = sm + OFF_GB + fb * GBS;
            float iv = gb[fh];
            float ov = gb[8 + fh];
            float gv = gb[16 + fh];
            float dv = gb[24 + fh];

            float w = dv;
            float facc = w * hist[0];
#pragma unroll
            for (int j = 2; j <= KDEPTH; ++j) {
                w *= ((float)(j - 1) - dv) * (1.0f / (float)j);
                facc = fmaf(w, hist[j - 1], facc);
            }
            float cnew = fmaf(iv, gv, facc);
            float hn = ov * tanhf(cnew);
#pragma unroll
            for (int j = KDEPTH - 1; j > 0; --j) hist[j] = hist[j - 1];
            hist[0] = cnew;
            dlast = dv;
            ((t & 1) ? hb1 : hb0)[(size_t)(Bb + fb) * HID + Hb + fh] = hn;
        }

        // ---- deferred y_{t-1} (waves 4-7), h_{t-1} is act h-part ----
        if (t > 0 && tid >= 256) {
            float acc = 0.f;
            const float* ap = sm + OFF_ACT + yb * SA + IN_DIM + ykc * 64;
            const float* wp = sm + OFF_WO + yoc * SOW + ykc * 64;
#pragma unroll
            for (int qq = 0; qq < 16; ++qq) {
                int q = (qq + ykc * 4) & 15;   // rotated: breaks bank aliasing
                float4 av = *(const float4*)(ap + q * 4);
                float4 wv = *(const float4*)(wp + q * 4);
                acc = dot4(av, wv, acc);
            }
            acc += __shfl_down(acc, 2);
            acc += __shfl_down(acc, 1);
            if (ykc == 0)
                ybase[((size_t)(t - 1) * BATCH + Bb + yb) * OUT_DIM + obase + yoc] =
                    acc + ybias;
        }

        grid.sync();
    }

    // ---- epilogue: y_{T-1} from final h, then hc_f / d_f ----
    for (int i = tid; i < 16 * 64; i += NTHR) {
        int row = i >> 6, q = i & 63;
        *(float4*)(sm + OFF_ACT + row * SA + IN_DIM + q * 4) =
            *(const float4*)(hfin + (size_t)(Bb + row) * HID + q * 4);
    }
    __syncthreads();

    if (tid >= 256) {
        float acc = 0.f;
        const float* ap = sm + OFF_ACT + yb * SA + IN_DIM + ykc * 64;
        const float* wp = sm + OFF_WO + yoc * SOW + ykc * 64;
#pragma unroll
        for (int qq = 0; qq < 16; ++qq) {
            int q = (qq + ykc * 4) & 15;
            float4 av = *(const float4*)(ap + q * 4);
            float4 wv = *(const float4*)(wp + q * 4);
            acc = dot4(av, wv, acc);
        }
        acc += __shfl_down(acc, 2);
        acc += __shfl_down(acc, 1);
        if (ykc == 0)
            ybase[((size_t)(T_STEPS - 1) * BATCH + Bb + yb) * OUT_DIM + obase + yoc] =
                acc + ybias;
    }

    if (tid < 128) {
#pragma unroll
        for (int j = 0; j < KDEPTH; ++j)
            hcf[((size_t)j * BATCH + Bb + fb) * HID + Hb + fh] = hist[j];
        dfin[(size_t)(Bb + fb) * HID + Hb + fh] = dlast;
    }
}

extern "C" void kernel_launch(void* const* d_in, const int* in_sizes, int n_in,
                              void* d_out, int out_size, void* d_ws, size_t ws_size,
                              hipStream_t stream)
{
    const float* x   = (const float*)d_in[0];
    const float* Wx  = (const float*)d_in[1];
    const float* Wh  = (const float*)d_in[2];
    const float* b   = (const float*)d_in[3];
    const float* Wdx = (const float*)d_in[4];
    const float* Wdh = (const float*)d_in[5];
    const float* bd  = (const float*)d_in[6];
    const float* Wo  = (const float*)d_in[7];
    const float* bo  = (const float*)d_in[8];
    float* out = (float*)d_out;

    (void)d_ws; (void)ws_size; (void)in_sizes; (void)n_in; (void)out_size;

    hipFuncSetAttribute((const void*)mlstm_frac_kernel,
                        hipFuncAttributeMaxDynamicSharedMemorySize, SMEM_BYTES);

    void* args[] = { (void*)&x, (void*)&Wx, (void*)&Wh, (void*)&b,
                     (void*)&Wdx, (void*)&Wdh, (void*)&bd, (void*)&Wo,
                     (void*)&bo, (void*)&out };

    hipLaunchCooperativeKernel((const void*)mlstm_frac_kernel,
                               dim3(NBLK), dim3(NTHR),
                               args, SMEM_BYTES, stream);
}

// Round 7
// 12360.291 us; speedup vs baseline: 2.8521x; 2.8521x over previous
//
#include <hip/hip_runtime.h>
#include <cmath>

#define T_STEPS 1024
#define BATCH   128
#define IN_DIM  128
#define HID     256
#define OUT_DIM 128
#define KDEPTH  32
#define KTOT    384

#define NBLK 256
#define NTHR 512

#define SA   388      // act row stride (floats)
#define WST  36       // wtT row stride: [384][36], k-major
#define SOW  260      // wo row stride
#define PSTR 36       // partials col stride
#define GBS  33       // gate buffer row stride

#define OFF_WT   0
#define OFF_WO   (384*WST)                 // 13824
#define OFF_ACT  (OFF_WO + 4*SOW)          // 14864
#define OFF_PART (OFF_ACT + 16*SA)         // 21072
#define OFF_GB   (OFF_PART + 16*16*PSTR)   // 30288
#define OFF_BC   (OFF_GB + 16*GBS)         // 30816
#define SMEM_FLOATS (OFF_BC + 32)
#define SMEM_BYTES  (SMEM_FLOATS*4)        // ~120.5 KB

// per-(bt,cgi) ready flags in d_ws, one per 64B line
#define FLAG_IDX(bt, cgi) (((bt) * 32 + (cgi)) * 16)

__device__ __forceinline__ float dot4(float4 a, float4 b, float acc) {
    acc = fmaf(a.x, b.x, acc);
    acc = fmaf(a.y, b.y, acc);
    acc = fmaf(a.z, b.z, acc);
    acc = fmaf(a.w, b.w, acc);
    return acc;
}

__global__ void init_flags_kernel(int* flags) {
    if (threadIdx.x < 256) flags[threadIdx.x * 16] = 0;
}

__global__ void __launch_bounds__(NTHR, 2)
mlstm_frac_kernel(const float* __restrict__ x,
                  const float* __restrict__ Wx,
                  const float* __restrict__ Wh,
                  const float* __restrict__ bvec,
                  const float* __restrict__ Wdx,
                  const float* __restrict__ Wdh,
                  const float* __restrict__ bd,
                  const float* __restrict__ Wo,
                  const float* __restrict__ bo,
                  float* __restrict__ out,
                  int* __restrict__ flags)
{
    extern __shared__ float sm[];

    const int tid = threadIdx.x;
    const int bt  = blockIdx.x >> 5;   // 0..7  batch tile
    const int cgi = blockIdx.x & 31;   // 0..31 col group
    const int Bb  = bt * 16;
    const int Hb  = cgi * 8;           // 8 h columns
    const int obase = cgi * 4;         // 4 y columns

    // ---- one-time: weights -> LDS ----
    for (int idx = tid; idx < 384 * 32; idx += NTHR) {
        int k = idx >> 5, c = idx & 31;
        int g = c >> 3, hl = c & 7;
        float v;
        if (g < 3) {
            int gcol = g * HID + Hb + hl;
            v = (k < IN_DIM) ? Wx[k * (3 * HID) + gcol]
                             : Wh[(k - IN_DIM) * (3 * HID) + gcol];
        } else {
            v = (k < IN_DIM) ? Wdx[k * HID + Hb + hl]
                             : Wdh[(k - IN_DIM) * HID + Hb + hl];
        }
        sm[OFF_WT + k * WST + c] = v;
    }
    for (int idx = tid; idx < 4 * 256; idx += NTHR) {
        int oc = idx >> 8, k = idx & 255;
        sm[OFF_WO + oc * SOW + k] = Wo[k * OUT_DIM + obase + oc];
    }
    if (tid < 32) {
        int g = tid >> 3, hl = tid & 7;
        sm[OFF_BC + tid] = (g < 3) ? bvec[g * HID + Hb + hl] : bd[Hb + hl];
    }

    // ---- roles ----
    const int kc = tid >> 5;          // 0..15
    const int pos = tid & 31;
    const int pr = pos >> 3;          // 0..3
    const int pc = pos & 7;           // 0..7
    const int k0 = kc * 24;
    const int xrow = tid >> 5;        // 0..15
    const int xcol = (tid & 31) * 4;  // 0..124
    const int fb = tid >> 3, fh = tid & 7;
    const int jy  = (tid >= 256) ? (tid - 256) : 0;
    const int yout = jy >> 2, ykc = jy & 3;
    const int yb = yout >> 2, yoc = yout & 3;
    const float ybias = bo[obase + yoc];

    float hist[KDEPTH];
#pragma unroll
    for (int j = 0; j < KDEPTH; ++j) hist[j] = 0.0f;

    // d_out layout: y (T*B*O) | h_f (B*H) | hc_f (K*B*H) | d_f (B*H)
    float* ybase = out;
    float* hfin  = out + (size_t)T_STEPS * BATCH * OUT_DIM;
    float* hcf   = hfin + BATCH * HID;
    float* dfin  = hcf + (size_t)KDEPTH * BATCH * HID;
    float* hb0 = hcf;    // borrowed; overwritten only after final wait
    float* hb1 = hfin;

    float dlast = 0.0f;

    // prefetch x_0 tile slot
    float4 xr = *(const float4*)(x + (size_t)(Bb + xrow) * IN_DIM + xcol);

    for (int t = 0; t < T_STEPS; ++t) {
        const float* hprev = (t & 1) ? hb0 : hb1;

        // ---- wait: h_{t-1} ready from the 32 producers of this bt ----
        // flag value after step tau is tau+1; stage of step t needs >= t.
        // t=0 passes immediately (flags zero-initialized).
        if (tid < 32) {
            while (__hip_atomic_load(&flags[FLAG_IDX(bt, tid)],
                                     __ATOMIC_RELAXED,
                                     __HIP_MEMORY_SCOPE_AGENT) < t)
                __builtin_amdgcn_s_sleep(2);
        }
        if (tid < 64)  // wave 0: single acquire fence (L1+L2 inv), then barrier
            __builtin_amdgcn_fence(__ATOMIC_ACQUIRE, "agent");
        __syncthreads();

        // ---- stage act[16][384] = x_t || h_{t-1} ----
        *(float4*)(sm + OFF_ACT + xrow * SA + xcol) = xr;
        for (int i = tid; i < 16 * 64; i += NTHR) {
            int row = i >> 6, q = i & 63;
            float4 v;
            if (t > 0)
                v = *(const float4*)(hprev + (size_t)(Bb + row) * HID + q * 4);
            else
                v = make_float4(0.f, 0.f, 0.f, 0.f);
            *(float4*)(sm + OFF_ACT + row * SA + IN_DIM + q * 4) = v;
        }
        {
            int tn = (t + 1 < T_STEPS) ? (t + 1) : t;
            xr = *(const float4*)(x + (size_t)tn * BATCH * IN_DIM
                                    + (size_t)(Bb + xrow) * IN_DIM + xcol);
        }
        __syncthreads();

        // ---- main GEMM: 16x32 outputs, 4x4 tile/thread, k in [k0,k0+24) ----
        float acc[4][4];
#pragma unroll
        for (int r = 0; r < 4; ++r)
#pragma unroll
            for (int c = 0; c < 4; ++c) acc[r][c] = 0.f;
        {
            const float* A0 = sm + OFF_ACT + (pr * 4) * SA + k0;
            const float* W0 = sm + OFF_WT + k0 * WST + pc * 4;
#pragma unroll
            for (int q = 0; q < 6; ++q) {
                float4 a0 = *(const float4*)(A0 + 0 * SA + q * 4);
                float4 a1 = *(const float4*)(A0 + 1 * SA + q * 4);
                float4 a2 = *(const float4*)(A0 + 2 * SA + q * 4);
                float4 a3 = *(const float4*)(A0 + 3 * SA + q * 4);
                float4 w0 = *(const float4*)(W0 + (q * 4 + 0) * WST);
                float4 w1 = *(const float4*)(W0 + (q * 4 + 1) * WST);
                float4 w2 = *(const float4*)(W0 + (q * 4 + 2) * WST);
                float4 w3 = *(const float4*)(W0 + (q * 4 + 3) * WST);
#define FMAROW(r, av)                                                      \
                acc[r][0] = fmaf(av.x, w0.x, acc[r][0]);                   \
                acc[r][1] = fmaf(av.x, w0.y, acc[r][1]);                   \
                acc[r][2] = fmaf(av.x, w0.z, acc[r][2]);                   \
                acc[r][3] = fmaf(av.x, w0.w, acc[r][3]);                   \
                acc[r][0] = fmaf(av.y, w1.x, acc[r][0]);                   \
                acc[r][1] = fmaf(av.y, w1.y, acc[r][1]);                   \
                acc[r][2] = fmaf(av.y, w1.z, acc[r][2]);                   \
                acc[r][3] = fmaf(av.y, w1.w, acc[r][3]);                   \
                acc[r][0] = fmaf(av.z, w2.x, acc[r][0]);                   \
                acc[r][1] = fmaf(av.z, w2.y, acc[r][1]);                   \
                acc[r][2] = fmaf(av.z, w2.z, acc[r][2]);                   \
                acc[r][3] = fmaf(av.z, w2.w, acc[r][3]);                   \
                acc[r][0] = fmaf(av.w, w3.x, acc[r][0]);                   \
                acc[r][1] = fmaf(av.w, w3.y, acc[r][1]);                   \
                acc[r][2] = fmaf(av.w, w3.z, acc[r][2]);                   \
                acc[r][3] = fmaf(av.w, w3.w, acc[r][3]);
                FMAROW(0, a0)
                FMAROW(1, a1)
                FMAROW(2, a2)
                FMAROW(3, a3)
#undef FMAROW
            }
        }
#pragma unroll
        for (int r = 0; r < 4; ++r) {
            *(float4*)(sm + OFF_PART + (kc * 16 + pr * 4 + r) * PSTR + pc * 4) =
                make_float4(acc[r][0], acc[r][1], acc[r][2], acc[r][3]);
        }
        __syncthreads();

        // ---- reduce 16 partials + bias + activation ----
        {
            int row = tid >> 5, c = tid & 31;
            const float* pp = sm + OFF_PART + row * PSTR + c;
            float s0 = 0.f, s1 = 0.f, s2 = 0.f, s3 = 0.f;
#pragma unroll
            for (int k4 = 0; k4 < 16; k4 += 4) {
                s0 += pp[(k4 + 0) * 16 * PSTR];
                s1 += pp[(k4 + 1) * 16 * PSTR];
                s2 += pp[(k4 + 2) * 16 * PSTR];
                s3 += pp[(k4 + 3) * 16 * PSTR];
            }
            float s = (s0 + s1) + (s2 + s3) + sm[OFF_BC + c];
            int g = c >> 3;
            float a;
            if (g == 2) a = tanhf(s);
            else {
                a = 1.0f / (1.0f + expf(-s));
                if (g == 3) a *= 0.5f;
            }
            sm[OFF_GB + row * GBS + c] = a;
        }
        __syncthreads();

        // ---- filter (waves 0-1): c/h update, h_t -> global ----
        if (tid < 128) {
            const float* gb = sm + OFF_GB + fb * GBS;
            float iv = gb[fh];
            float ov = gb[8 + fh];
            float gv = gb[16 + fh];
            float dv = gb[24 + fh];

            float w = dv;
            float facc = w * hist[0];
#pragma unroll
            for (int j = 2; j <= KDEPTH; ++j) {
                w *= ((float)(j - 1) - dv) * (1.0f / (float)j);
                facc = fmaf(w, hist[j - 1], facc);
            }
            float cnew = fmaf(iv, gv, facc);
            float hn = ov * tanhf(cnew);
#pragma unroll
            for (int j = KDEPTH - 1; j > 0; --j) hist[j] = hist[j - 1];
            hist[0] = cnew;
            dlast = dv;
            ((t & 1) ? hb1 : hb0)[(size_t)(Bb + fb) * HID + Hb + fh] = hn;
        }

        // ---- deferred y_{t-1} (waves 4-7) ----
        if (t > 0 && tid >= 256) {
            float acc = 0.f;
            const float* ap = sm + OFF_ACT + yb * SA + IN_DIM + ykc * 64;
            const float* wp = sm + OFF_WO + yoc * SOW + ykc * 64;
#pragma unroll
            for (int qq = 0; qq < 16; ++qq) {
                int q = (qq + ykc * 4) & 15;
                float4 av = *(const float4*)(ap + q * 4);
                float4 wv = *(const float4*)(wp + q * 4);
                acc = dot4(av, wv, acc);
            }
            acc += __shfl_down(acc, 2);
            acc += __shfl_down(acc, 1);
            if (ykc == 0)
                ybase[((size_t)(t - 1) * BATCH + Bb + yb) * OUT_DIM + obase + yoc] =
                    acc + ybias;
        }

        // ---- publish: h stores drained by syncthreads, then release flag ----
        __syncthreads();
        if (tid == 0)
            __hip_atomic_store(&flags[FLAG_IDX(bt, cgi)], t + 1,
                               __ATOMIC_RELEASE, __HIP_MEMORY_SCOPE_AGENT);
    }

    // ---- epilogue: wait for all same-bt peers to finish step T-1 ----
    if (tid < 32) {
        while (__hip_atomic_load(&flags[FLAG_IDX(bt, tid)],
                                 __ATOMIC_RELAXED,
                                 __HIP_MEMORY_SCOPE_AGENT) < T_STEPS)
            __builtin_amdgcn_s_sleep(2);
    }
    if (tid < 64)
        __builtin_amdgcn_fence(__ATOMIC_ACQUIRE, "agent");
    __syncthreads();

    // y_{T-1} from final h
    for (int i = tid; i < 16 * 64; i += NTHR) {
        int row = i >> 6, q = i & 63;
        *(float4*)(sm + OFF_ACT + row * SA + IN_DIM + q * 4) =
            *(const float4*)(hfin + (size_t)(Bb + row) * HID + q * 4);
    }
    __syncthreads();

    if (tid >= 256) {
        float acc = 0.f;
        const float* ap = sm + OFF_ACT + yb * SA + IN_DIM + ykc * 64;
        const float* wp = sm + OFF_WO + yoc * SOW + ykc * 64;
#pragma unroll
        for (int qq = 0; qq < 16; ++qq) {
            int q = (qq + ykc * 4) & 15;
            float4 av = *(const float4*)(ap + q * 4);
            float4 wv = *(const float4*)(wp + q * 4);
            acc = dot4(av, wv, acc);
        }
        acc += __shfl_down(acc, 2);
        acc += __shfl_down(acc, 1);
        if (ykc == 0)
            ybase[((size_t)(T_STEPS - 1) * BATCH + Bb + yb) * OUT_DIM + obase + yoc] =
                acc + ybias;
    }

    if (tid < 128) {
#pragma unroll
        for (int j = 0; j < KDEPTH; ++j)
            hcf[((size_t)j * BATCH + Bb + fb) * HID + Hb + fh] = hist[j];
        dfin[(size_t)(Bb + fb) * HID + Hb + fh] = dlast;
    }
}

extern "C" void kernel_launch(void* const* d_in, const int* in_sizes, int n_in,
                              void* d_out, int out_size, void* d_ws, size_t ws_size,
                              hipStream_t stream)
{
    const float* x   = (const float*)d_in[0];
    const float* Wx  = (const float*)d_in[1];
    const float* Wh  = (const float*)d_in[2];
    const float* b   = (const float*)d_in[3];
    const float* Wdx = (const float*)d_in[4];
    const float* Wdh = (const float*)d_in[5];
    const float* bd  = (const float*)d_in[6];
    const float* Wo  = (const float*)d_in[7];
    const float* bo  = (const float*)d_in[8];
    float* out = (float*)d_out;
    int* flags = (int*)d_ws;

    (void)in_sizes; (void)n_in; (void)out_size; (void)ws_size;

    hipFuncSetAttribute((const void*)mlstm_frac_kernel,
                        hipFuncAttributeMaxDynamicSharedMemorySize, SMEM_BYTES);

    // zero the 256 ready-flags (d_ws is re-poisoned before every launch)
    hipLaunchKernelGGL(init_flags_kernel, dim3(1), dim3(256), 0, stream, flags);

    void* args[] = { (void*)&x, (void*)&Wx, (void*)&Wh, (void*)&b,
                     (void*)&Wdx, (void*)&Wdh, (void*)&bd, (void*)&Wo,
                     (void*)&bo, (void*)&out, (void*)&flags };

    hipLaunchCooperativeKernel((const void*)mlstm_frac_kernel,
                               dim3(NBLK), dim3(NTHR),
                               args, SMEM_BYTES, stream);
}

// Round 11
// 4686.657 us; speedup vs baseline: 7.5220x; 2.6373x over previous
//
#include <hip/hip_runtime.h>
#include <cmath>

#define T_STEPS 1024
#define BATCH   128
#define IN_DIM  128
#define HID     256
#define OUT_DIM 128
#define KDEPTH  32
#define KTOT    384

#define NBLK 256
#define NTHR 512

#define SA   388      // act row stride (floats)
#define WST  36       // wtT row stride: [384][36], k-major
#define SOW  260      // wo row stride
#define PSTR 36       // partials col stride
#define GBS  33       // gate buffer row stride

#define OFF_WT   0
#define OFF_WO   (384*WST)                 // 13824
#define OFF_ACT  (OFF_WO + 4*SOW)          // 14864
#define OFF_PART (OFF_ACT + 16*SA)         // 21072
#define OFF_GB   (OFF_PART + 16*16*PSTR)   // 30288
#define OFF_BC   (OFF_GB + 16*GBS)         // 30816
#define SMEM_FLOATS (OFF_BC + 32)
#define SMEM_BYTES  (SMEM_FLOATS*4)        // ~120.5 KB

// 8 per-bt step counters in d_ws, one per 64B line
#define CNT_IDX(bt) ((bt) * 16)

__device__ __forceinline__ float dot4(float4 a, float4 b, float acc) {
    acc = fmaf(a.x, b.x, acc);
    acc = fmaf(a.y, b.y, acc);
    acc = fmaf(a.z, b.z, acc);
    acc = fmaf(a.w, b.w, acc);
    return acc;
}

__global__ void init_flags_kernel(int* cnt) {
    if (threadIdx.x < 256) cnt[threadIdx.x * 16] = 0;
}

__global__ void __launch_bounds__(NTHR, 2)
mlstm_frac_kernel(const float* __restrict__ x,
                  const float* __restrict__ Wx,
                  const float* __restrict__ Wh,
                  const float* __restrict__ bvec,
                  const float* __restrict__ Wdx,
                  const float* __restrict__ Wdh,
                  const float* __restrict__ bd,
                  const float* __restrict__ Wo,
                  const float* __restrict__ bo,
                  float* __restrict__ out,
                  int* __restrict__ cnt)
{
    extern __shared__ float sm[];

    const int tid = threadIdx.x;
    // XCD swizzle: all 32 blocks of a bt land on one XCD (round-robin bid%8)
    const int bt  = blockIdx.x & 7;    // 0..7  batch tile
    const int cgi = blockIdx.x >> 3;   // 0..31 col group
    const int Bb  = bt * 16;
    const int Hb  = cgi * 8;           // 8 h columns
    const int obase = cgi * 4;         // 4 y columns

    // ---- one-time: weights -> LDS ----
    for (int idx = tid; idx < 384 * 32; idx += NTHR) {
        int k = idx >> 5, c = idx & 31;
        int g = c >> 3, hl = c & 7;
        float v;
        if (g < 3) {
            int gcol = g * HID + Hb + hl;
            v = (k < IN_DIM) ? Wx[k * (3 * HID) + gcol]
                             : Wh[(k - IN_DIM) * (3 * HID) + gcol];
        } else {
            v = (k < IN_DIM) ? Wdx[k * HID + Hb + hl]
                             : Wdh[(k - IN_DIM) * HID + Hb + hl];
        }
        sm[OFF_WT + k * WST + c] = v;
    }
    for (int idx = tid; idx < 4 * 256; idx += NTHR) {
        int oc = idx >> 8, k = idx & 255;
        sm[OFF_WO + oc * SOW + k] = Wo[k * OUT_DIM + obase + oc];
    }
    if (tid < 32) {
        int g = tid >> 3, hl = tid & 7;
        sm[OFF_BC + tid] = (g < 3) ? bvec[g * HID + Hb + hl] : bd[Hb + hl];
    }

    // ---- roles ----
    const int kc = tid >> 5;          // 0..15
    const int pos = tid & 31;
    const int pr = pos >> 3;          // 0..3
    const int pc = pos & 7;           // 0..7
    const int k0 = kc * 24;
    const int xrow = tid >> 5;        // 0..15
    const int xcol = (tid & 31) * 4;  // 0..124
    // h staging: row = tid>>5 (0..15), 4 x u64 per thread, coalesced per j
    const int hrow = tid >> 5;
    const int hl32 = tid & 31;
    const int fb = tid >> 3, fh = tid & 7;
    const int jy  = (tid >= 256) ? (tid - 256) : 0;
    const int yout = jy >> 2, ykc = jy & 3;
    const int yb = yout >> 2, yoc = yout & 3;
    const float ybias = bo[obase + yoc];

    float hist[KDEPTH];
#pragma unroll
    for (int j = 0; j < KDEPTH; ++j) hist[j] = 0.0f;

    // d_out layout: y (T*B*O) | h_f (B*H) | hc_f (K*B*H) | d_f (B*H)
    float* ybase = out;
    float* hfin  = out + (size_t)T_STEPS * BATCH * OUT_DIM;
    float* hcf   = hfin + BATCH * HID;
    float* dfin  = hcf + (size_t)KDEPTH * BATCH * HID;
    float* hb0 = hcf;    // borrowed; overwritten only after final wait
    float* hb1 = hfin;

    float dlast = 0.0f;

    // prefetch x_0 tile slot
    float4 xr = *(const float4*)(x + (size_t)(Bb + xrow) * IN_DIM + xcol);

    for (int t = 0; t < T_STEPS; ++t) {
        const float* hprev = (t & 1) ? hb0 : hb1;

        // ---- wait: all 32 producers of this bt finished step t-1 ----
        // counter value after all blocks finish step tau is 32*(tau+1);
        // step t requires >= 32*t (t=0 passes: zero-init).
        if (tid == 0) {
            while (__hip_atomic_load(&cnt[CNT_IDX(bt)],
                                     __ATOMIC_RELAXED,
                                     __HIP_MEMORY_SCOPE_AGENT) < 32 * t)
                __builtin_amdgcn_s_sleep(2);
        }
        __syncthreads();

        // ---- stage act[16][384] = x_t || h_{t-1} ----
        *(float4*)(sm + OFF_ACT + xrow * SA + xcol) = xr;
        {
            // h-part via agent-scope atomic u64 loads (coherence point,
            // no cache maintenance needed)
            const unsigned long long* hsrc =
                (const unsigned long long*)(hprev + (size_t)Bb * HID);
#pragma unroll
            for (int j = 0; j < 4; ++j) {
                int u = hl32 + j * 32;            // u64 index in row, 0..127
                unsigned long long v = 0ull;
                if (t > 0)
                    v = __hip_atomic_load(&hsrc[(size_t)hrow * 128 + u],
                                          __ATOMIC_RELAXED,
                                          __HIP_MEMORY_SCOPE_AGENT);
                *(unsigned long long*)(sm + OFF_ACT + hrow * SA + IN_DIM + u * 2) = v;
            }
        }
        {
            int tn = (t + 1 < T_STEPS) ? (t + 1) : t;
            xr = *(const float4*)(x + (size_t)tn * BATCH * IN_DIM
                                    + (size_t)(Bb + xrow) * IN_DIM + xcol);
        }
        __syncthreads();

        // ---- main GEMM: 16x32 outputs, 4x4 tile/thread, k in [k0,k0+24) ----
        float acc[4][4];
#pragma unroll
        for (int r = 0; r < 4; ++r)
#pragma unroll
            for (int c = 0; c < 4; ++c) acc[r][c] = 0.f;
        {
            const float* A0 = sm + OFF_ACT + (pr * 4) * SA + k0;
            const float* W0 = sm + OFF_WT + k0 * WST + pc * 4;
#pragma unroll
            for (int q = 0; q < 6; ++q) {
                float4 a0 = *(const float4*)(A0 + 0 * SA + q * 4);
                float4 a1 = *(const float4*)(A0 + 1 * SA + q * 4);
                float4 a2 = *(const float4*)(A0 + 2 * SA + q * 4);
                float4 a3 = *(const float4*)(A0 + 3 * SA + q * 4);
                float4 w0 = *(const float4*)(W0 + (q * 4 + 0) * WST);
                float4 w1 = *(const float4*)(W0 + (q * 4 + 1) * WST);
                float4 w2 = *(const float4*)(W0 + (q * 4 + 2) * WST);
                float4 w3 = *(const float4*)(W0 + (q * 4 + 3) * WST);
#define FMAROW(r, av)                                                      \
                acc[r][0] = fmaf(av.x, w0.x, acc[r][0]);                   \
                acc[r][1] = fmaf(av.x, w0.y, acc[r][1]);                   \
                acc[r][2] = fmaf(av.x, w0.z, acc[r][2]);                   \
                acc[r][3] = fmaf(av.x, w0.w, acc[r][3]);                   \
                acc[r][0] = fmaf(av.y, w1.x, acc[r][0]);                   \
                acc[r][1] = fmaf(av.y, w1.y, acc[r][1]);                   \
                acc[r][2] = fmaf(av.y, w1.z, acc[r][2]);                   \
                acc[r][3] = fmaf(av.y, w1.w, acc[r][3]);                   \
                acc[r][0] = fmaf(av.z, w2.x, acc[r][0]);                   \
                acc[r][1] = fmaf(av.z, w2.y, acc[r][1]);                   \
                acc[r][2] = fmaf(av.z, w2.z, acc[r][2]);                   \
                acc[r][3] = fmaf(av.z, w2.w, acc[r][3]);                   \
                acc[r][0] = fmaf(av.w, w3.x, acc[r][0]);                   \
                acc[r][1] = fmaf(av.w, w3.y, acc[r][1]);                   \
                acc[r][2] = fmaf(av.w, w3.z, acc[r][2]);                   \
                acc[r][3] = fmaf(av.w, w3.w, acc[r][3]);
                FMAROW(0, a0)
                FMAROW(1, a1)
                FMAROW(2, a2)
                FMAROW(3, a3)
#undef FMAROW
            }
        }
#pragma unroll
        for (int r = 0; r < 4; ++r) {
            *(float4*)(sm + OFF_PART + (kc * 16 + pr * 4 + r) * PSTR + pc * 4) =
                make_float4(acc[r][0], acc[r][1], acc[r][2], acc[r][3]);
        }
        __syncthreads();

        // ---- reduce 16 partials + bias + activation ----
        {
            int row = tid >> 5, c = tid & 31;
            const float* pp = sm + OFF_PART + row * PSTR + c;
            float s0 = 0.f, s1 = 0.f, s2 = 0.f, s3 = 0.f;
#pragma unroll
            for (int k4 = 0; k4 < 16; k4 += 4) {
                s0 += pp[(k4 + 0) * 16 * PSTR];
                s1 += pp[(k4 + 1) * 16 * PSTR];
                s2 += pp[(k4 + 2) * 16 * PSTR];
                s3 += pp[(k4 + 3) * 16 * PSTR];
            }
            float s = (s0 + s1) + (s2 + s3) + sm[OFF_BC + c];
            int g = c >> 3;
            float a;
            if (g == 2) a = tanhf(s);
            else {
                a = 1.0f / (1.0f + expf(-s));
                if (g == 3) a *= 0.5f;
            }
            sm[OFF_GB + row * GBS + c] = a;
        }
        __syncthreads();

        // ---- filter (waves 0-1): c/h update, h_t -> global (write-through) --
        if (tid < 128) {
            const float* gb = sm + OFF_GB + fb * GBS;
            float iv = gb[fh];
            float ov = gb[8 + fh];
            float gv = gb[16 + fh];
            float dv = gb[24 + fh];

            float w = dv;
            float facc = w * hist[0];
#pragma unroll
            for (int j = 2; j <= KDEPTH; ++j) {
                w *= ((float)(j - 1) - dv) * (1.0f / (float)j);
                facc = fmaf(w, hist[j - 1], facc);
            }
            float cnew = fmaf(iv, gv, facc);
            float hn = ov * tanhf(cnew);
#pragma unroll
            for (int j = KDEPTH - 1; j > 0; --j) hist[j] = hist[j - 1];
            hist[0] = cnew;
            dlast = dv;
            float* dst = (t & 1) ? hb1 : hb0;
            union { float f; unsigned int u; } cv; cv.f = hn;
            __hip_atomic_store(
                (unsigned int*)&dst[(size_t)(Bb + fb) * HID + Hb + fh], cv.u,
                __ATOMIC_RELAXED, __HIP_MEMORY_SCOPE_AGENT);
        }

        // ---- publish ASAP: barrier drains vmcnt (h stores acked at the
        // coherence point), then one counter bump; y-GEMM runs after,
        // off the critical path.
        __syncthreads();
        if (tid == 0)
            __hip_atomic_fetch_add(&cnt[CNT_IDX(bt)], 1,
                                   __ATOMIC_RELAXED, __HIP_MEMORY_SCOPE_AGENT);

        // ---- deferred y_{t-1} (waves 4-7); act not overwritten until the
        // post-wait barrier of the next iteration.
        if (t > 0 && tid >= 256) {
            float acc = 0.f;
            const float* ap = sm + OFF_ACT + yb * SA + IN_DIM + ykc * 64;
            const float* wp = sm + OFF_WO + yoc * SOW + ykc * 64;
#pragma unroll
            for (int qq = 0; qq < 16; ++qq) {
                int q = (qq + ykc * 4) & 15;
                float4 av = *(const float4*)(ap + q * 4);
                float4 wv = *(const float4*)(wp + q * 4);
                acc = dot4(av, wv, acc);
            }
            acc += __shfl_down(acc, 2);
            acc += __shfl_down(acc, 1);
            if (ykc == 0)
                ybase[((size_t)(t - 1) * BATCH + Bb + yb) * OUT_DIM + obase + yoc] =
                    acc + ybias;
        }
    }

    // ---- epilogue: wait for all same-bt peers to finish step T-1 ----
    if (tid == 0) {
        while (__hip_atomic_load(&cnt[CNT_IDX(bt)],
                                 __ATOMIC_RELAXED,
                                 __HIP_MEMORY_SCOPE_AGENT) < 32 * T_STEPS)
            __builtin_amdgcn_s_sleep(2);
    }
    __syncthreads();

    // y_{T-1} from final h (hfin; read via atomic u64 for coherence)
    {
        const unsigned long long* hsrc =
            (const unsigned long long*)(hfin + (size_t)Bb * HID);
#pragma unroll
        for (int j = 0; j < 4; ++j) {
            int u = hl32 + j * 32;
            unsigned long long v =
                __hip_atomic_load(&hsrc[(size_t)hrow * 128 + u],
                                  __ATOMIC_RELAXED, __HIP_MEMORY_SCOPE_AGENT);
            *(unsigned long long*)(sm + OFF_ACT + hrow * SA + IN_DIM + u * 2) = v;
        }
    }
    __syncthreads();

    if (tid >= 256) {
        float acc = 0.f;
        const float* ap = sm + OFF_ACT + yb * SA + IN_DIM + ykc * 64;
        const float* wp = sm + OFF_WO + yoc * SOW + ykc * 64;
#pragma unroll
        for (int qq = 0; qq < 16; ++qq) {
            int q = (qq + ykc * 4) & 15;
            float4 av = *(const float4*)(ap + q * 4);
            float4 wv = *(const float4*)(wp + q * 4);
            acc = dot4(av, wv, acc);
        }
        acc += __shfl_down(acc, 2);
        acc += __shfl_down(acc, 1);
        if (ykc == 0)
            ybase[((size_t)(T_STEPS - 1) * BATCH + Bb + yb) * OUT_DIM + obase + yoc] =
                acc + ybias;
    }

    if (tid < 128) {
#pragma unroll
        for (int j = 0; j < KDEPTH; ++j)
            hcf[((size_t)j * BATCH + Bb + fb) * HID + Hb + fh] = hist[j];
        dfin[(size_t)(Bb + fb) * HID + Hb + fh] = dlast;
    }
}

extern "C" void kernel_launch(void* const* d_in, const int* in_sizes, int n_in,
                              void* d_out, int out_size, void* d_ws, size_t ws_size,
                              hipStream_t stream)
{
    const float* x   = (const float*)d_in[0];
    const float* Wx  = (const float*)d_in[1];
    const float* Wh  = (const float*)d_in[2];
    const float* b   = (const float*)d_in[3];
    const float* Wdx = (const float*)d_in[4];
    const float* Wdh = (const float*)d_in[5];
    const float* bd  = (const float*)d_in[6];
    const float* Wo  = (const float*)d_in[7];
    const float* bo  = (const float*)d_in[8];
    float* out = (float*)d_out;
    int* cnt = (int*)d_ws;

    (void)in_sizes; (void)n_in; (void)out_size; (void)ws_size;

    hipFuncSetAttribute((const void*)mlstm_frac_kernel,
                        hipFuncAttributeMaxDynamicSharedMemorySize, SMEM_BYTES);

    // zero the counters (d_ws is re-poisoned before every launch)
    hipLaunchKernelGGL(init_flags_kernel, dim3(1), dim3(256), 0, stream, cnt);

    void* args[] = { (void*)&x, (void*)&Wx, (void*)&Wh, (void*)&b,
                     (void*)&Wdx, (void*)&Wdh, (void*)&bd, (void*)&Wo,
                     (void*)&bo, (void*)&out, (void*)&cnt };

    hipLaunchCooperativeKernel((const void*)mlstm_frac_kernel,
                               dim3(NBLK), dim3(NTHR),
                               args, SMEM_BYTES, stream);
}